// Round 1
// baseline (345.152 us; speedup 1.0000x reference)
//
#include <hip/hip_runtime.h>
#include <stdint.h>

// Problem constants (reference: B=2, C=4, SPATIAL=(128,128,128), N_PTS=32, THR=0.5)
#define Bn 2
#define Cn 4
#define Sn (128 * 128 * 128)   // 2^21 voxels per (b,c)
#define NPTS 32
#define NBINS 1025             // probs in (0.5, 1] -> one binade; (bits-0x3F000000)>>13 in [0,1024]
#define THRf 0.5f
#define PB 4096                // voxels per block in the fused pass
#define BT 512                 // threads/block: 8 waves; ~34KB LDS -> 4 blk/CU (wave-limit) = 32 waves/CU
#define FB 512                 // per-class survivor cap in the selection epilogue (expected m ~ 40)

__device__ __forceinline__ int bin_of_bits(unsigned int u) {
    return (int)((u - 0x3F000000u) >> 13);
}

// Softmax over the 4 classes at one voxel; mirrors jax.nn.softmax exactly
// (exp(x-max)/sum, sequential sum c=0..3). Only the argmax class can exceed 0.5.
__device__ __forceinline__ void softmax_argmax4(float l0, float l1, float l2, float l3,
                                                int* cm_out, float* p_out) {
    float m = fmaxf(fmaxf(l0, l1), fmaxf(l2, l3));
    float e0 = expf(l0 - m);
    float e1 = expf(l1 - m);
    float e2 = expf(l2 - m);
    float e3 = expf(l3 - m);
    float s = ((e0 + e1) + e2) + e3;
    float em = e0; int cm = 0;
    if (e1 > em) { em = e1; cm = 1; }
    if (e2 > em) { em = e2; cm = 2; }
    if (e3 > em) { em = e3; cm = 3; }
    *cm_out = cm;
    *p_out = em / s;
}

// Single fused kernel.
// Phases 1-3 are the proven streaming pass (register-resident packed candidates,
// per-class local radix hist, local cutoff -> superset of global top-32, one global
// atomic reservation per (block,class), emit survivors from registers).
// NEW (R8): the per-(b,c) exact selection that used to be a second kernel
// (select_emit, 8 nearly-empty blocks after a grid-wide drain) now runs in the
// LAST-finishing block of each batch via the device done-counter. This removes one
// kernel launch + full inter-kernel drain, and batch-b selection overlaps the other
// batch's remaining streaming blocks. Correctness argument is unchanged: bins
// strictly above the superset-derived global cutoff are complete in the superset,
// so ranking within the filtered set is exact for the top-32.
__global__ __launch_bounds__(BT) void fused_kernel(const float* __restrict__ logits,
                                                   unsigned int* __restrict__ cnt,
                                                   uint2* __restrict__ cand,
                                                   int cap,
                                                   unsigned int* __restrict__ done,
                                                   int* __restrict__ out) {
    __shared__ unsigned int lh[Cn * NBINS];   // 16.4 KB: per-class radix hist (both passes)
    __shared__ unsigned int lcut[Cn], cls_cnt[Cn], cls_base[Cn], cls_pos[Cn];
    __shared__ unsigned int s_old;
    // epilogue-only (last block per batch); counted in static LDS: total ~34 KB -> 4 blk/CU
    __shared__ uint2 fbuf[Cn * FB];           // 16.4 KB survivor buffer
    __shared__ uint2 stopk[Cn * NPTS];        // 1 KB exact top-32 per class
    __shared__ int s_n[Cn];
    __shared__ unsigned int s_T[Cn], s_m[Cn];
    __shared__ int pre[Cn + 1];

    const int b = blockIdx.y;
    const int t = threadIdx.x;
    const int lane = t & 63;
    for (int j = t; j < Cn * NBINS; j += BT) lh[j] = 0u;
    if (t < Cn) { lcut[t] = 0u; cls_cnt[t] = 0u; cls_pos[t] = 0u; }
    __syncthreads();

    // phase 1: stream voxels (float4 x 4 class streams); results stay in registers
    const float* base = logits + (size_t)b * Cn * Sn;
    const float4* s0 = (const float4*)base;
    const float4* s1 = (const float4*)(base + Sn);
    const float4* s2 = (const float4*)(base + 2 * Sn);
    const float4* s3 = (const float4*)(base + 3 * Sn);
    const int qs = blockIdx.x * (PB / 4);
    unsigned int pk[PB / BT];   // 8 packed results per thread
    #pragma unroll
    for (int it = 0; it < PB / 4 / BT; ++it) {   // 2 iterations
        int q = qs + it * BT + t;
        float4 v0 = s0[q], v1 = s1[q], v2 = s2[q], v3 = s3[q];
        const float* a0 = &v0.x; const float* a1 = &v1.x;
        const float* a2 = &v2.x; const float* a3 = &v3.x;
        #pragma unroll
        for (int k = 0; k < 4; ++k) {
            int cm; float p;
            softmax_argmax4(a0[k], a1[k], a2[k], a3[k], &cm, &p);
            unsigned int pv = 0u;
            if (p > THRf) {
                unsigned int off = __float_as_uint(p) - 0x3F000000u;  // 1..0x800000
                atomicAdd(&lh[cm * NBINS + (int)(off >> 13)], 1u);    // no-return ds_add
                pv = (off << 2) | (unsigned int)cm;                   // 26 bits, nonzero
            }
            pk[it * 4 + k] = pv;
        }
    }
    __syncthreads();

    // phase 2: wave w (w<4) computes local cutoff for class w (64 lanes x 17 bins >= 1025).
    // Entries below the local cutoff have >=32 strictly-greater local entries ->
    // global rank >= 32 -> safe to drop. Union over blocks is a superset of top-32.
    // The break-time acc = count of entries in bins >= lcut = exact emit count.
    {
        const int wave = t >> 6;
        if (wave < Cn) {
            const unsigned int* h = &lh[wave * NBINS];
            const int lo = lane * 17;
            unsigned int cs = 0;
            #pragma unroll
            for (int k = 0; k < 17; ++k) {
                int bin = lo + k;
                if (bin < NBINS) cs += h[bin];
            }
            unsigned int S = cs;  // inclusive suffix sum over lanes [lane..63]
            #pragma unroll
            for (int off = 1; off < 64; off <<= 1) {
                unsigned int v = __shfl_down(S, off, 64);
                if (lane + off < 64) S += v;
            }
            unsigned int suf = S - cs;
            if (S >= NPTS && suf < NPTS) {   // exactly one lane (when total >= 32)
                unsigned int acc = suf;
                int hi = min(lo + 16, NBINS - 1);
                for (int bin = hi; bin >= lo; --bin) {
                    acc += h[bin];
                    if (acc >= NPTS) {
                        lcut[wave] = (unsigned int)bin;
                        cls_cnt[wave] = acc;
                        break;
                    }
                }
            }
            if (lane == 0 && S < NPTS) cls_cnt[wave] = S;  // total<32: lcut=0, emit all
        }
    }
    __syncthreads();

    // reservation: one global atomic per (block, class)
    if (t < Cn && cls_cnt[t] > 0)
        cls_base[t] = atomicAdd(&cnt[b * Cn + t], cls_cnt[t]);
    __syncthreads();

    // phase 3: emit survivors straight from registers (~130/block total)
    #pragma unroll
    for (int j = 0; j < PB / BT; ++j) {
        unsigned int pv = pk[j];
        if (pv != 0u) {
            unsigned int cm = pv & 3u;
            if ((pv >> 15) >= lcut[cm]) {   // pv>>15 == p_off>>13 == bin
                unsigned int pos = cls_base[cm] + atomicAdd(&cls_pos[cm], 1u);
                if (pos < (unsigned int)cap) {
                    int it = j >> 2, k = j & 3;
                    unsigned int idx = (unsigned int)((qs + it * BT + t) * 4 + k);
                    cand[(size_t)(b * Cn + cm) * cap + pos] =
                        make_uint2(0x3F000000u + (pv >> 2), idx);
                }
            }
        }
    }

    // ---- epilogue: last-finishing block of this batch does the exact selection ----
    __threadfence();   // release: cand/cnt writes visible before done increment
    __syncthreads();
    if (t == 0) s_old = atomicAdd(&done[b], 1u);
    __syncthreads();
    if (s_old != (unsigned int)(gridDim.x - 1)) return;   // block-uniform branch
    __threadfence();   // acquire: see all other blocks' cand/cnt writes

    // re-init shared for the selection pass
    for (int j = t; j < Cn * NBINS; j += BT) lh[j] = 0u;
    if (t < Cn) {
        s_n[t] = min((int)cnt[b * Cn + t], cap);
        s_T[t] = 0u;
        s_m[t] = 0u;
    }
    __syncthreads();

    // pass A: per-class global histogram over all emitted candidates of batch b
    for (int c = 0; c < Cn; ++c) {
        const uint2* src = cand + (size_t)(b * Cn + c) * cap;
        const int n = s_n[c];
        for (int j = t; j < n; j += BT)
            atomicAdd(&lh[c * NBINS + bin_of_bits(src[j].x)], 1u);
    }
    __syncthreads();

    // exact global cutoff per class: wave w scans class w
    {
        const int wave = t >> 6;
        if (wave < Cn) {
            const unsigned int* h = &lh[wave * NBINS];
            const int lo = lane * 17;
            unsigned int cs = 0;
            #pragma unroll
            for (int k = 0; k < 17; ++k) {
                int bin = lo + k;
                if (bin < NBINS) cs += h[bin];
            }
            unsigned int S = cs;
            #pragma unroll
            for (int off = 1; off < 64; off <<= 1) {
                unsigned int v = __shfl_down(S, off, 64);
                if (lane + off < 64) S += v;
            }
            unsigned int suf = S - cs;
            if (S >= NPTS && suf < NPTS) {
                unsigned int acc = suf;
                int hi = min(lo + 16, NBINS - 1);
                for (int bin = hi; bin >= lo; --bin) {
                    acc += h[bin];
                    if (acc >= NPTS) { s_T[wave] = (unsigned int)bin; break; }
                }
            }
            // S < NPTS: s_T stays 0 -> keep everything
        }
    }
    __syncthreads();

    // pass B: filter survivors (bins >= global cutoff) into LDS, ~40 per class
    for (int c = 0; c < Cn; ++c) {
        const uint2* src = cand + (size_t)(b * Cn + c) * cap;
        const int n = s_n[c];
        const unsigned int T = s_T[c];
        for (int j = t; j < n; j += BT) {
            uint2 e = src[j];
            if ((unsigned int)bin_of_bits(e.x) >= T) {
                unsigned int pos = atomicAdd(&s_m[c], 1u);
                if (pos < FB) fbuf[c * FB + pos] = e;
            }
        }
    }
    __syncthreads();

    // exact rank with jax tie-break (higher prob first; equal prob -> lower idx first)
    for (int c = 0; c < Cn; ++c) {
        const int m = min((int)s_m[c], FB);
        const int vn = min(s_n[c], NPTS);
        for (int i = t; i < m; i += BT) {
            uint2 e = fbuf[c * FB + i];
            int rank = 0;
            for (int j = 0; j < m; ++j) {
                uint2 o = fbuf[c * FB + j];
                rank += (int)((o.x > e.x) || (o.x == e.x && o.y < e.y));
            }
            if (rank < vn) stopk[c * NPTS + rank] = e;   // ranks distinct: idx unique per class
        }
    }
    if (t == 0) {
        int acc = 0;
        for (int oc = 0; oc < Cn; ++oc) {
            pre[oc] = acc;
            acc += min(s_n[(oc + 1) & 3], NPTS);   // class visit order [1,2,3,0]
        }
        pre[Cn] = acc;
    }
    __syncthreads();

    // emit 128 output slots for batch b (compacted in class order, padding label -1)
    if (t < Cn * NPTS) {
        const int j = t;
        int label = -1, z = 0, y = 0, x = 0;
        if (j < pre[Cn]) {
            int oc = 0;
            while (j >= pre[oc + 1]) ++oc;
            int c = (oc + 1) & 3;
            int r = j - pre[oc];
            uint2 e = stopk[c * NPTS + r];
            int idx = (int)e.y;
            z = idx >> 14;          // idx / (128*128)
            y = (idx >> 7) & 127;   // (idx / 128) % 128
            x = idx & 127;          // idx % 128
            label = c;
        }
        int* coords = out;                       // 2*128*3 = 768 ints
        int* labels = out + Bn * Cn * NPTS * 3;  // then 2*128 = 256 ints
        int bo = b * Cn * NPTS + j;
        coords[bo * 3 + 0] = z;
        coords[bo * 3 + 1] = y;
        coords[bo * 3 + 2] = x;
        labels[bo] = label;
    }
}

extern "C" void kernel_launch(void* const* d_in, const int* in_sizes, int n_in,
                              void* d_out, int out_size, void* d_ws, size_t ws_size,
                              hipStream_t stream) {
    const float* logits = (const float*)d_in[0];
    int* out = (int*)d_out;

    // Workspace layout
    unsigned int* cnt = (unsigned int*)d_ws;             // 8 u32  @0
    unsigned int* done = cnt + Bn * Cn;                  // 2 u32  @32
    uint2* cand = (uint2*)(done + Bn);                   // @40 (8-aligned)
    size_t fixed = (size_t)((char*)cand - (char*)d_ws);
    int cap = (int)((ws_size - fixed) / (Bn * Cn * sizeof(uint2)));
    if (cap > (1 << 18)) cap = 1 << 18;   // 256k entries/bc >> the ~18k expected
    if (cap < 4096) cap = 4096;

    // Zero cnt (8) + done (2) counters only (workspace is harness-poisoned every iter)
    hipMemsetAsync(cnt, 0, (Bn * Cn + Bn) * sizeof(unsigned int), stream);

    dim3 grid(Sn / PB, Bn);   // (512, 2) = 1024 blocks, fully co-resident at 4 blk/CU
    fused_kernel<<<grid, BT, 0, stream>>>(logits, cnt, cand, cap, done, out);
}

// Round 2
// 185.431 us; speedup vs baseline: 1.8613x; 1.8613x over previous
//
#include <hip/hip_runtime.h>
#include <stdint.h>

// Problem constants (reference: B=2, C=4, SPATIAL=(128,128,128), N_PTS=32, THR=0.5)
#define Bn 2
#define Cn 4
#define Sn (128 * 128 * 128)   // 2^21 voxels per (b,c)
#define NPTS 32
#define NBINS 1025             // probs in (0.5, 1] -> one binade; (bits-0x3F000000)>>13 in [0,1024]
#define THRf 0.5f
#define PB 4096                // voxels per block in the fused pass
#define BT 512                 // threads/block: 8 waves; ~34KB LDS -> 4 blk/CU (wave-limit) = 32 waves/CU
#define FB 512                 // per-class survivor cap in the selection epilogue (expected m ~ 40)

__device__ __forceinline__ int bin_of_bits(unsigned int u) {
    return (int)((u - 0x3F000000u) >> 13);
}

// Softmax over the 4 classes at one voxel; mirrors jax.nn.softmax exactly
// (exp(x-max)/sum, sequential sum c=0..3). Only the argmax class can exceed 0.5.
__device__ __forceinline__ void softmax_argmax4(float l0, float l1, float l2, float l3,
                                                int* cm_out, float* p_out) {
    float m = fmaxf(fmaxf(l0, l1), fmaxf(l2, l3));
    float e0 = expf(l0 - m);
    float e1 = expf(l1 - m);
    float e2 = expf(l2 - m);
    float e3 = expf(l3 - m);
    float s = ((e0 + e1) + e2) + e3;
    float em = e0; int cm = 0;
    if (e1 > em) { em = e1; cm = 1; }
    if (e2 > em) { em = e2; cm = 2; }
    if (e3 > em) { em = e3; cm = 3; }
    *cm_out = cm;
    *p_out = em / s;
}

// Single fused kernel.
// Phases 1-3 are the proven streaming pass. The per-(b,c) exact selection runs in
// the LAST-finishing block of each batch via the device done-counter.
//
// R9 lesson (the 345us regression): __threadfence() in EVERY block compiles to a
// device-scope release = buffer_wbl2 (full L2 writeback) per wave -> 8192 L2 walks
// ~ 270us of stall (VALUBusy 4.7%, HBM 1.6%, all idle). Fix: the only writes that
// must cross the block boundary are ~130 cand entries/block + the cnt atomics.
// cand entries are now written with device-scope relaxed atomic stores (sc0 sc1,
// write-through past L2), so NO release fence is needed: __syncthreads() drains
// each wave's vmcnt (stores complete at the coherence point) before the done
// increment is issued. cnt/done atomics are already device-scope RMWs. Only the
// 2 consumer blocks (one per batch) pay a full __threadfence (buffer_inv) to
// discard possibly-stale clean L2 lines before re-reading cand/cnt.
__global__ __launch_bounds__(BT) void fused_kernel(const float* __restrict__ logits,
                                                   unsigned int* __restrict__ cnt,
                                                   uint2* __restrict__ cand,
                                                   int cap,
                                                   unsigned int* __restrict__ done,
                                                   int* __restrict__ out) {
    __shared__ unsigned int lh[Cn * NBINS];   // 16.4 KB: per-class radix hist (both passes)
    __shared__ unsigned int lcut[Cn], cls_cnt[Cn], cls_base[Cn], cls_pos[Cn];
    __shared__ unsigned int s_old;
    // epilogue-only (last block per batch); counted in static LDS: total ~34 KB -> 4 blk/CU
    __shared__ uint2 fbuf[Cn * FB];           // 16.4 KB survivor buffer
    __shared__ uint2 stopk[Cn * NPTS];        // 1 KB exact top-32 per class
    __shared__ int s_n[Cn];
    __shared__ unsigned int s_T[Cn], s_m[Cn];
    __shared__ int pre[Cn + 1];

    const int b = blockIdx.y;
    const int t = threadIdx.x;
    const int lane = t & 63;
    for (int j = t; j < Cn * NBINS; j += BT) lh[j] = 0u;
    if (t < Cn) { lcut[t] = 0u; cls_cnt[t] = 0u; cls_pos[t] = 0u; }
    __syncthreads();

    // phase 1: stream voxels (float4 x 4 class streams); results stay in registers
    const float* base = logits + (size_t)b * Cn * Sn;
    const float4* s0 = (const float4*)base;
    const float4* s1 = (const float4*)(base + Sn);
    const float4* s2 = (const float4*)(base + 2 * Sn);
    const float4* s3 = (const float4*)(base + 3 * Sn);
    const int qs = blockIdx.x * (PB / 4);
    unsigned int pk[PB / BT];   // 8 packed results per thread
    #pragma unroll
    for (int it = 0; it < PB / 4 / BT; ++it) {   // 2 iterations
        int q = qs + it * BT + t;
        float4 v0 = s0[q], v1 = s1[q], v2 = s2[q], v3 = s3[q];
        const float* a0 = &v0.x; const float* a1 = &v1.x;
        const float* a2 = &v2.x; const float* a3 = &v3.x;
        #pragma unroll
        for (int k = 0; k < 4; ++k) {
            int cm; float p;
            softmax_argmax4(a0[k], a1[k], a2[k], a3[k], &cm, &p);
            unsigned int pv = 0u;
            if (p > THRf) {
                unsigned int off = __float_as_uint(p) - 0x3F000000u;  // 1..0x800000
                atomicAdd(&lh[cm * NBINS + (int)(off >> 13)], 1u);    // no-return ds_add
                pv = (off << 2) | (unsigned int)cm;                   // 26 bits, nonzero
            }
            pk[it * 4 + k] = pv;
        }
    }
    __syncthreads();

    // phase 2: wave w (w<4) computes local cutoff for class w (64 lanes x 17 bins >= 1025).
    // Entries below the local cutoff have >=32 strictly-greater local entries ->
    // global rank >= 32 -> safe to drop. Union over blocks is a superset of top-32.
    // The break-time acc = count of entries in bins >= lcut = exact emit count.
    {
        const int wave = t >> 6;
        if (wave < Cn) {
            const unsigned int* h = &lh[wave * NBINS];
            const int lo = lane * 17;
            unsigned int cs = 0;
            #pragma unroll
            for (int k = 0; k < 17; ++k) {
                int bin = lo + k;
                if (bin < NBINS) cs += h[bin];
            }
            unsigned int S = cs;  // inclusive suffix sum over lanes [lane..63]
            #pragma unroll
            for (int off = 1; off < 64; off <<= 1) {
                unsigned int v = __shfl_down(S, off, 64);
                if (lane + off < 64) S += v;
            }
            unsigned int suf = S - cs;
            if (S >= NPTS && suf < NPTS) {   // exactly one lane (when total >= 32)
                unsigned int acc = suf;
                int hi = min(lo + 16, NBINS - 1);
                for (int bin = hi; bin >= lo; --bin) {
                    acc += h[bin];
                    if (acc >= NPTS) {
                        lcut[wave] = (unsigned int)bin;
                        cls_cnt[wave] = acc;
                        break;
                    }
                }
            }
            if (lane == 0 && S < NPTS) cls_cnt[wave] = S;  // total<32: lcut=0, emit all
        }
    }
    __syncthreads();

    // reservation: one global atomic per (block, class) (device-scope sc1 RMW)
    if (t < Cn && cls_cnt[t] > 0)
        cls_base[t] = atomicAdd(&cnt[b * Cn + t], cls_cnt[t]);
    __syncthreads();

    // phase 3: emit survivors straight from registers (~130/block total).
    // Device-scope relaxed atomic stores (sc0 sc1): visible at the coherence point
    // once each wave's vmcnt drains -> no per-block release fence needed.
    #pragma unroll
    for (int j = 0; j < PB / BT; ++j) {
        unsigned int pv = pk[j];
        if (pv != 0u) {
            unsigned int cm = pv & 3u;
            if ((pv >> 15) >= lcut[cm]) {   // pv>>15 == p_off>>13 == bin
                unsigned int pos = cls_base[cm] + atomicAdd(&cls_pos[cm], 1u);
                if (pos < (unsigned int)cap) {
                    int it = j >> 2, k = j & 3;
                    unsigned int idx = (unsigned int)((qs + it * BT + t) * 4 + k);
                    unsigned long long packed =
                        ((unsigned long long)idx << 32) | (0x3F000000u + (pv >> 2));
                    __hip_atomic_store(
                        (unsigned long long*)&cand[(size_t)(b * Cn + cm) * cap + pos],
                        packed, __ATOMIC_RELAXED, __HIP_MEMORY_SCOPE_AGENT);
                }
            }
        }
    }

    // ---- epilogue: last-finishing block of this batch does the exact selection ----
    // __syncthreads() drains every wave's vmcnt (sc1 stores complete at coherence
    // point) before t==0 issues the done RMW -> release ordering without wbl2.
    __syncthreads();
    if (t == 0) s_old = atomicAdd(&done[b], 1u);
    __syncthreads();
    if (s_old != (unsigned int)(gridDim.x - 1)) return;   // block-uniform branch
    __threadfence();   // acquire (buffer_inv): only 2 blocks device-wide pay this

    // re-init shared for the selection pass
    for (int j = t; j < Cn * NBINS; j += BT) lh[j] = 0u;
    if (t < Cn) {
        s_n[t] = min((int)cnt[b * Cn + t], cap);
        s_T[t] = 0u;
        s_m[t] = 0u;
    }
    __syncthreads();

    // pass A: per-class global histogram over all emitted candidates of batch b
    for (int c = 0; c < Cn; ++c) {
        const uint2* src = cand + (size_t)(b * Cn + c) * cap;
        const int n = s_n[c];
        for (int j = t; j < n; j += BT)
            atomicAdd(&lh[c * NBINS + bin_of_bits(src[j].x)], 1u);
    }
    __syncthreads();

    // exact global cutoff per class: wave w scans class w
    {
        const int wave = t >> 6;
        if (wave < Cn) {
            const unsigned int* h = &lh[wave * NBINS];
            const int lo = lane * 17;
            unsigned int cs = 0;
            #pragma unroll
            for (int k = 0; k < 17; ++k) {
                int bin = lo + k;
                if (bin < NBINS) cs += h[bin];
            }
            unsigned int S = cs;
            #pragma unroll
            for (int off = 1; off < 64; off <<= 1) {
                unsigned int v = __shfl_down(S, off, 64);
                if (lane + off < 64) S += v;
            }
            unsigned int suf = S - cs;
            if (S >= NPTS && suf < NPTS) {
                unsigned int acc = suf;
                int hi = min(lo + 16, NBINS - 1);
                for (int bin = hi; bin >= lo; --bin) {
                    acc += h[bin];
                    if (acc >= NPTS) { s_T[wave] = (unsigned int)bin; break; }
                }
            }
            // S < NPTS: s_T stays 0 -> keep everything
        }
    }
    __syncthreads();

    // pass B: filter survivors (bins >= global cutoff) into LDS, ~40 per class
    for (int c = 0; c < Cn; ++c) {
        const uint2* src = cand + (size_t)(b * Cn + c) * cap;
        const int n = s_n[c];
        const unsigned int T = s_T[c];
        for (int j = t; j < n; j += BT) {
            uint2 e = src[j];
            if ((unsigned int)bin_of_bits(e.x) >= T) {
                unsigned int pos = atomicAdd(&s_m[c], 1u);
                if (pos < FB) fbuf[c * FB + pos] = e;
            }
        }
    }
    __syncthreads();

    // exact rank with jax tie-break (higher prob first; equal prob -> lower idx first)
    for (int c = 0; c < Cn; ++c) {
        const int m = min((int)s_m[c], FB);
        const int vn = min(s_n[c], NPTS);
        for (int i = t; i < m; i += BT) {
            uint2 e = fbuf[c * FB + i];
            int rank = 0;
            for (int j = 0; j < m; ++j) {
                uint2 o = fbuf[c * FB + j];
                rank += (int)((o.x > e.x) || (o.x == e.x && o.y < e.y));
            }
            if (rank < vn) stopk[c * NPTS + rank] = e;   // ranks distinct: idx unique per class
        }
    }
    if (t == 0) {
        int acc = 0;
        for (int oc = 0; oc < Cn; ++oc) {
            pre[oc] = acc;
            acc += min(s_n[(oc + 1) & 3], NPTS);   // class visit order [1,2,3,0]
        }
        pre[Cn] = acc;
    }
    __syncthreads();

    // emit 128 output slots for batch b (compacted in class order, padding label -1)
    if (t < Cn * NPTS) {
        const int j = t;
        int label = -1, z = 0, y = 0, x = 0;
        if (j < pre[Cn]) {
            int oc = 0;
            while (j >= pre[oc + 1]) ++oc;
            int c = (oc + 1) & 3;
            int r = j - pre[oc];
            uint2 e = stopk[c * NPTS + r];
            int idx = (int)e.y;
            z = idx >> 14;          // idx / (128*128)
            y = (idx >> 7) & 127;   // (idx / 128) % 128
            x = idx & 127;          // idx % 128
            label = c;
        }
        int* coords = out;                       // 2*128*3 = 768 ints
        int* labels = out + Bn * Cn * NPTS * 3;  // then 2*128 = 256 ints
        int bo = b * Cn * NPTS + j;
        coords[bo * 3 + 0] = z;
        coords[bo * 3 + 1] = y;
        coords[bo * 3 + 2] = x;
        labels[bo] = label;
    }
}

extern "C" void kernel_launch(void* const* d_in, const int* in_sizes, int n_in,
                              void* d_out, int out_size, void* d_ws, size_t ws_size,
                              hipStream_t stream) {
    const float* logits = (const float*)d_in[0];
    int* out = (int*)d_out;

    // Workspace layout
    unsigned int* cnt = (unsigned int*)d_ws;             // 8 u32  @0
    unsigned int* done = cnt + Bn * Cn;                  // 2 u32  @32
    uint2* cand = (uint2*)(done + Bn);                   // @40 (8-aligned)
    size_t fixed = (size_t)((char*)cand - (char*)d_ws);
    int cap = (int)((ws_size - fixed) / (Bn * Cn * sizeof(uint2)));
    if (cap > (1 << 18)) cap = 1 << 18;   // 256k entries/bc >> the ~18k expected
    if (cap < 4096) cap = 4096;

    // Zero cnt (8) + done (2) counters only (workspace is harness-poisoned every iter)
    hipMemsetAsync(cnt, 0, (Bn * Cn + Bn) * sizeof(unsigned int), stream);

    dim3 grid(Sn / PB, Bn);   // (512, 2) = 1024 blocks, fully co-resident at 4 blk/CU
    fused_kernel<<<grid, BT, 0, stream>>>(logits, cnt, cand, cap, done, out);
}

// Round 3
// 149.113 us; speedup vs baseline: 2.3147x; 1.2436x over previous
//
#include <hip/hip_runtime.h>
#include <stdint.h>

// Problem constants (reference: B=2, C=4, SPATIAL=(128,128,128), N_PTS=32, THR=0.5)
#define Bn 2
#define Cn 4
#define Sn (128 * 128 * 128)   // 2^21 voxels per (b,c)
#define NPTS 32
#define NBINS 1025             // probs in (0.5, 1] -> one binade; (bits-0x3F000000)>>13 in [0,1024]
#define THRf 0.5f
#define PB 4096                // voxels per block in the fused pass
#define BT 512                 // threads/block: 8 waves; ~34KB LDS -> 4 blk/CU (wave-limit) = 32 waves/CU
#define FB 512                 // per-class survivor cap in the selection epilogue (expected m ~ 200)

__device__ __forceinline__ int bin_of_bits(unsigned int u) {
    return (int)((u - 0x3F000000u) >> 13);
}

// Softmax over the 4 classes at one voxel; mirrors jax.nn.softmax exactly
// (exp(x-max)/sum, sequential sum c=0..3). Only the argmax class can exceed 0.5.
__device__ __forceinline__ void softmax_argmax4(float l0, float l1, float l2, float l3,
                                                int* cm_out, float* p_out) {
    float m = fmaxf(fmaxf(l0, l1), fmaxf(l2, l3));
    float e0 = expf(l0 - m);
    float e1 = expf(l1 - m);
    float e2 = expf(l2 - m);
    float e3 = expf(l3 - m);
    float s = ((e0 + e1) + e2) + e3;
    float em = e0; int cm = 0;
    if (e1 > em) { em = e1; cm = 1; }
    if (e2 > em) { em = e2; cm = 2; }
    if (e3 > em) { em = e3; cm = 3; }
    *cm_out = cm;
    *p_out = em / s;
}

// Single fused kernel.
// R9 lesson: per-block __threadfence = buffer_wbl2 storm (345us). Fixed with
// device-scope sc1 stores for cand + done-counter release via barrier vmcnt drain.
// R10 lesson (the 114us version): OccupancyPercent 22.8% decomposes as ~26us
// streaming @32 waves/CU + ~88us of 2-block epilogue tail -- the epilogue re-read
// 72k cand entries TWICE (hist + filter) with one 512-thread block, one dependent
// L2-cold load per iteration. Fix:
//   (a) phase 2.5: blocks publish their local surviving-bin histogram into a
//       global hist gh[b][c][bin] (~35 fire-and-forget atomics/class/block,
//       overlapped with streaming) == exactly the epilogue's old pass A.
//   (b) epilogue: read gh (16KB), exact cutoff, then ONE filtered pass over cand
//       with 8-way unrolled independent loads (MLP), rank, emit. ~10us.
__global__ __launch_bounds__(BT) void fused_kernel(const float* __restrict__ logits,
                                                   unsigned int* __restrict__ cnt,
                                                   unsigned int* __restrict__ gh,
                                                   uint2* __restrict__ cand,
                                                   int cap,
                                                   unsigned int* __restrict__ done,
                                                   int* __restrict__ out) {
    __shared__ unsigned int lh[Cn * NBINS];   // 16.4 KB: per-class radix hist (both passes)
    __shared__ unsigned int lcut[Cn], cls_cnt[Cn], cls_base[Cn], cls_pos[Cn];
    __shared__ unsigned int s_old;
    // epilogue-only (last block per batch); counted in static LDS: total ~34 KB -> 4 blk/CU
    __shared__ uint2 fbuf[Cn * FB];           // 16.4 KB survivor buffer
    __shared__ uint2 stopk[Cn * NPTS];        // 1 KB exact top-32 per class
    __shared__ int s_n[Cn];
    __shared__ unsigned int s_T[Cn], s_m[Cn];
    __shared__ int pre[Cn + 1];

    const int b = blockIdx.y;
    const int t = threadIdx.x;
    const int lane = t & 63;
    for (int j = t; j < Cn * NBINS; j += BT) lh[j] = 0u;
    if (t < Cn) { lcut[t] = 0u; cls_cnt[t] = 0u; cls_pos[t] = 0u; }
    __syncthreads();

    // phase 1: stream voxels (float4 x 4 class streams); results stay in registers
    const float* base = logits + (size_t)b * Cn * Sn;
    const float4* s0 = (const float4*)base;
    const float4* s1 = (const float4*)(base + Sn);
    const float4* s2 = (const float4*)(base + 2 * Sn);
    const float4* s3 = (const float4*)(base + 3 * Sn);
    const int qs = blockIdx.x * (PB / 4);
    unsigned int pk[PB / BT];   // 8 packed results per thread
    #pragma unroll
    for (int it = 0; it < PB / 4 / BT; ++it) {   // 2 iterations
        int q = qs + it * BT + t;
        float4 v0 = s0[q], v1 = s1[q], v2 = s2[q], v3 = s3[q];
        const float* a0 = &v0.x; const float* a1 = &v1.x;
        const float* a2 = &v2.x; const float* a3 = &v3.x;
        #pragma unroll
        for (int k = 0; k < 4; ++k) {
            int cm; float p;
            softmax_argmax4(a0[k], a1[k], a2[k], a3[k], &cm, &p);
            unsigned int pv = 0u;
            if (p > THRf) {
                unsigned int off = __float_as_uint(p) - 0x3F000000u;  // 1..0x800000
                atomicAdd(&lh[cm * NBINS + (int)(off >> 13)], 1u);    // no-return ds_add
                pv = (off << 2) | (unsigned int)cm;                   // 26 bits, nonzero
            }
            pk[it * 4 + k] = pv;
        }
    }
    __syncthreads();

    // phase 2: wave w (w<4) computes local cutoff for class w (64 lanes x 17 bins >= 1025).
    // Entries below the local cutoff have >=32 strictly-greater local entries ->
    // global rank >= 32 -> safe to drop. Union over blocks is a superset of top-32.
    // The break-time acc = count of entries in bins >= lcut = exact emit count.
    {
        const int wave = t >> 6;
        if (wave < Cn) {
            const unsigned int* h = &lh[wave * NBINS];
            const int lo = lane * 17;
            unsigned int cs = 0;
            #pragma unroll
            for (int k = 0; k < 17; ++k) {
                int bin = lo + k;
                if (bin < NBINS) cs += h[bin];
            }
            unsigned int S = cs;  // inclusive suffix sum over lanes [lane..63]
            #pragma unroll
            for (int off = 1; off < 64; off <<= 1) {
                unsigned int v = __shfl_down(S, off, 64);
                if (lane + off < 64) S += v;
            }
            unsigned int suf = S - cs;
            if (S >= NPTS && suf < NPTS) {   // exactly one lane (when total >= 32)
                unsigned int acc = suf;
                int hi = min(lo + 16, NBINS - 1);
                for (int bin = hi; bin >= lo; --bin) {
                    acc += h[bin];
                    if (acc >= NPTS) {
                        lcut[wave] = (unsigned int)bin;
                        cls_cnt[wave] = acc;
                        break;
                    }
                }
            }
            if (lane == 0 && S < NPTS) cls_cnt[wave] = S;  // total<32: lcut=0, emit all
        }
    }
    __syncthreads();

    // phase 2.5: publish surviving bins (bin >= lcut, nonzero) into the global
    // per-(b,c) histogram -- exactly the histogram of all emitted candidates.
    // Fire-and-forget device-scope atomics, ~35 per class per block.
    {
        const int wave = t >> 6;
        if (wave < Cn) {
            const unsigned int* h = &lh[wave * NBINS];
            unsigned int* g = gh + (size_t)(b * Cn + wave) * NBINS;
            for (int bin = (int)lcut[wave] + lane; bin < NBINS; bin += 64) {
                unsigned int v = h[bin];
                if (v) atomicAdd(&g[bin], v);
            }
        }
    }
    // reservation: one global atomic per (block, class) (device-scope sc1 RMW)
    if (t < Cn && cls_cnt[t] > 0)
        cls_base[t] = atomicAdd(&cnt[b * Cn + t], cls_cnt[t]);
    __syncthreads();

    // phase 3: emit survivors straight from registers (~130/block total).
    // Device-scope relaxed atomic stores (sc0 sc1): visible at the coherence point
    // once each wave's vmcnt drains -> no per-block release fence needed.
    #pragma unroll
    for (int j = 0; j < PB / BT; ++j) {
        unsigned int pv = pk[j];
        if (pv != 0u) {
            unsigned int cm = pv & 3u;
            if ((pv >> 15) >= lcut[cm]) {   // pv>>15 == p_off>>13 == bin
                unsigned int pos = cls_base[cm] + atomicAdd(&cls_pos[cm], 1u);
                if (pos < (unsigned int)cap) {
                    int it = j >> 2, k = j & 3;
                    unsigned int idx = (unsigned int)((qs + it * BT + t) * 4 + k);
                    unsigned long long packed =
                        ((unsigned long long)idx << 32) | (0x3F000000u + (pv >> 2));
                    __hip_atomic_store(
                        (unsigned long long*)&cand[(size_t)(b * Cn + cm) * cap + pos],
                        packed, __ATOMIC_RELAXED, __HIP_MEMORY_SCOPE_AGENT);
                }
            }
        }
    }

    // ---- epilogue: last-finishing block of this batch does the exact selection ----
    // __syncthreads() drains every wave's vmcnt (sc1 stores + gh/cnt atomics
    // complete at the coherence point) before t==0 issues the done RMW ->
    // release ordering without any wbl2.
    __syncthreads();
    if (t == 0) s_old = atomicAdd(&done[b], 1u);
    __syncthreads();
    if (s_old != (unsigned int)(gridDim.x - 1)) return;   // block-uniform branch
    __threadfence();   // acquire (buffer_inv): only 2 blocks device-wide pay this

    // load the global histogram (already complete) + per-class counts
    for (int j = t; j < Cn * NBINS; j += BT)
        lh[j] = gh[(size_t)b * Cn * NBINS + j];
    if (t < Cn) {
        s_n[t] = min((int)cnt[b * Cn + t], cap);
        s_T[t] = 0u;
        s_m[t] = 0u;
    }
    __syncthreads();

    // exact global cutoff per class: wave w scans class w
    {
        const int wave = t >> 6;
        if (wave < Cn) {
            const unsigned int* h = &lh[wave * NBINS];
            const int lo = lane * 17;
            unsigned int cs = 0;
            #pragma unroll
            for (int k = 0; k < 17; ++k) {
                int bin = lo + k;
                if (bin < NBINS) cs += h[bin];
            }
            unsigned int S = cs;
            #pragma unroll
            for (int off = 1; off < 64; off <<= 1) {
                unsigned int v = __shfl_down(S, off, 64);
                if (lane + off < 64) S += v;
            }
            unsigned int suf = S - cs;
            if (S >= NPTS && suf < NPTS) {
                unsigned int acc = suf;
                int hi = min(lo + 16, NBINS - 1);
                for (int bin = hi; bin >= lo; --bin) {
                    acc += h[bin];
                    if (acc >= NPTS) { s_T[wave] = (unsigned int)bin; break; }
                }
            }
            // S < NPTS: s_T stays 0 -> keep everything
        }
    }
    __syncthreads();

    // single filtered pass: 8-way unrolled independent loads for MLP (the R10
    // killer was one dependent L2-cold load per iteration). ~200 survivors/class.
    for (int c = 0; c < Cn; ++c) {
        const uint2* src = cand + (size_t)(b * Cn + c) * cap;
        const int n = s_n[c];
        const unsigned int T = s_T[c];
        for (int j0 = t; j0 < n; j0 += BT * 8) {
            uint2 e0, e1, e2, e3, e4, e5, e6, e7;
            if (j0 + 0 * BT < n) e0 = src[j0 + 0 * BT];
            if (j0 + 1 * BT < n) e1 = src[j0 + 1 * BT];
            if (j0 + 2 * BT < n) e2 = src[j0 + 2 * BT];
            if (j0 + 3 * BT < n) e3 = src[j0 + 3 * BT];
            if (j0 + 4 * BT < n) e4 = src[j0 + 4 * BT];
            if (j0 + 5 * BT < n) e5 = src[j0 + 5 * BT];
            if (j0 + 6 * BT < n) e6 = src[j0 + 6 * BT];
            if (j0 + 7 * BT < n) e7 = src[j0 + 7 * BT];
            #define FILT(EK, KK)                                                  \
                if (j0 + (KK) * BT < n &&                                         \
                    (unsigned int)bin_of_bits(EK.x) >= T) {                       \
                    unsigned int pos = atomicAdd(&s_m[c], 1u);                    \
                    if (pos < FB) fbuf[c * FB + pos] = EK;                        \
                }
            FILT(e0, 0) FILT(e1, 1) FILT(e2, 2) FILT(e3, 3)
            FILT(e4, 4) FILT(e5, 5) FILT(e6, 6) FILT(e7, 7)
            #undef FILT
        }
    }
    __syncthreads();

    // exact rank with jax tie-break (higher prob first; equal prob -> lower idx first)
    for (int c = 0; c < Cn; ++c) {
        const int m = min((int)s_m[c], FB);
        const int vn = min(s_n[c], NPTS);
        for (int i = t; i < m; i += BT) {
            uint2 e = fbuf[c * FB + i];
            int rank = 0;
            for (int j = 0; j < m; ++j) {
                uint2 o = fbuf[c * FB + j];
                rank += (int)((o.x > e.x) || (o.x == e.x && o.y < e.y));
            }
            if (rank < vn) stopk[c * NPTS + rank] = e;   // ranks distinct: idx unique per class
        }
    }
    if (t == 0) {
        int acc = 0;
        for (int oc = 0; oc < Cn; ++oc) {
            pre[oc] = acc;
            acc += min(s_n[(oc + 1) & 3], NPTS);   // class visit order [1,2,3,0]
        }
        pre[Cn] = acc;
    }
    __syncthreads();

    // emit 128 output slots for batch b (compacted in class order, padding label -1)
    if (t < Cn * NPTS) {
        const int j = t;
        int label = -1, z = 0, y = 0, x = 0;
        if (j < pre[Cn]) {
            int oc = 0;
            while (j >= pre[oc + 1]) ++oc;
            int c = (oc + 1) & 3;
            int r = j - pre[oc];
            uint2 e = stopk[c * NPTS + r];
            int idx = (int)e.y;
            z = idx >> 14;          // idx / (128*128)
            y = (idx >> 7) & 127;   // (idx / 128) % 128
            x = idx & 127;          // idx % 128
            label = c;
        }
        int* coords = out;                       // 2*128*3 = 768 ints
        int* labels = out + Bn * Cn * NPTS * 3;  // then 2*128 = 256 ints
        int bo = b * Cn * NPTS + j;
        coords[bo * 3 + 0] = z;
        coords[bo * 3 + 1] = y;
        coords[bo * 3 + 2] = x;
        labels[bo] = label;
    }
}

extern "C" void kernel_launch(void* const* d_in, const int* in_sizes, int n_in,
                              void* d_out, int out_size, void* d_ws, size_t ws_size,
                              hipStream_t stream) {
    const float* logits = (const float*)d_in[0];
    int* out = (int*)d_out;

    // Workspace layout
    unsigned int* cnt = (unsigned int*)d_ws;             // 8 u32   @0
    unsigned int* done = cnt + Bn * Cn;                  // 2 u32   @32
    unsigned int* gh = done + Bn;                        // 8*1025  @40
    uint2* cand = (uint2*)(gh + Bn * Cn * NBINS);        // @32840 (8-aligned)
    size_t fixed = (size_t)((char*)cand - (char*)d_ws);
    int cap = (int)((ws_size - fixed) / (Bn * Cn * sizeof(uint2)));
    if (cap > (1 << 18)) cap = 1 << 18;   // 256k entries/bc >> the ~18k expected
    if (cap < 4096) cap = 4096;

    // Zero cnt (8) + done (2) + gh (8200) counters (~33 KB; workspace is
    // harness-poisoned every iter)
    hipMemsetAsync(cnt, 0, (size_t)(Bn * Cn + Bn + Bn * Cn * NBINS) * sizeof(unsigned int),
                   stream);

    dim3 grid(Sn / PB, Bn);   // (512, 2) = 1024 blocks, fully co-resident at 4 blk/CU
    fused_kernel<<<grid, BT, 0, stream>>>(logits, cnt, gh, cand, cap, done, out);
}

// Round 4
// 128.221 us; speedup vs baseline: 2.6918x; 1.1629x over previous
//
#include <hip/hip_runtime.h>
#include <stdint.h>

// Problem constants (reference: B=2, C=4, SPATIAL=(128,128,128), N_PTS=32, THR=0.5)
#define Bn 2
#define Cn 4
#define Sn (128 * 128 * 128)   // 2^21 voxels per (b,c)
#define NPTS 32
#define NBINS 1025             // probs in (0.5, 1] -> one binade; (bits-0x3F000000)>>13 in [0,1024]
#define THRf 0.5f
#define PB 4096                // voxels per block in the fused pass
#define BT 512                 // threads/block: 8 waves; ~26KB LDS; wave-limit -> 4 blk/CU
#define FB 1024                // single-class survivor cap in the selection epilogue (expected ~80)

__device__ __forceinline__ int bin_of_bits(unsigned int u) {
    return (int)((u - 0x3F000000u) >> 13);
}

// Softmax over the 4 classes at one voxel; mirrors jax.nn.softmax exactly
// (exp(x-max)/sum, sequential sum c=0..3). Only the argmax class can exceed 0.5.
__device__ __forceinline__ void softmax_argmax4(float l0, float l1, float l2, float l3,
                                                int* cm_out, float* p_out) {
    float m = fmaxf(fmaxf(l0, l1), fmaxf(l2, l3));
    float e0 = expf(l0 - m);
    float e1 = expf(l1 - m);
    float e2 = expf(l2 - m);
    float e3 = expf(l3 - m);
    float s = ((e0 + e1) + e2) + e3;
    float em = e0; int cm = 0;
    if (e1 > em) { em = e1; cm = 1; }
    if (e2 > em) { em = e2; cm = 2; }
    if (e3 > em) { em = e3; cm = 3; }
    *cm_out = cm;
    *p_out = em / s;
}

// Single fused kernel. Lessons ledger:
// R9:  per-block __threadfence = buffer_wbl2 storm (345us). -> sc1 stores for cand,
//      release via barrier vmcnt-drain before the done RMW; acquire fence only in
//      consumer blocks.
// R10: 2-block epilogue re-read cand TWICE, dependent L2-cold loads -> 88us tail.
//      -> phase 2.5 publishes the candidate histogram (gh) during streaming.
// R11 (this round): tail still ~49us: ONE block/batch did the filter over 72k
//      entries, and the guarded "unroll" serialized its loads. Fix:
//      (a) the LAST FOUR finishers of each batch each select ONE class (4x
//          parallel, one spin on <=3 stragglers -- schedulable since >=1020
//          slots have freed, so no co-residency assumption);
//      (b) branch-free index-clamped 8-deep load batches (true MLP);
//      (c) class blocks write topk/validn via sc1 stores; a done2 counter picks
//          the last class-finisher to emit the final 128 slots.
__global__ __launch_bounds__(BT) void fused_kernel(const float* __restrict__ logits,
                                                   unsigned int* __restrict__ cnt,
                                                   unsigned int* __restrict__ gh,
                                                   uint2* __restrict__ cand,
                                                   int cap,
                                                   unsigned int* __restrict__ done,
                                                   unsigned int* __restrict__ done2,
                                                   unsigned int* __restrict__ validn,
                                                   uint2* __restrict__ topk,
                                                   int* __restrict__ out) {
    __shared__ unsigned int lh[Cn * NBINS];   // 16.4 KB: per-class radix hist
    __shared__ unsigned int lcut[Cn], cls_cnt[Cn], cls_base[Cn], cls_pos[Cn];
    __shared__ unsigned int s_old;
    // epilogue-only: single-class survivor buffer + scalars
    __shared__ uint2 fbuf[FB];                // 8.2 KB
    __shared__ unsigned int s_T, s_m;
    __shared__ int pre[Cn + 1];

    const int b = blockIdx.y;
    const int t = threadIdx.x;
    const int lane = t & 63;
    for (int j = t; j < Cn * NBINS; j += BT) lh[j] = 0u;
    if (t < Cn) { lcut[t] = 0u; cls_cnt[t] = 0u; cls_pos[t] = 0u; }
    __syncthreads();

    // phase 1: stream voxels (float4 x 4 class streams); results stay in registers
    const float* base = logits + (size_t)b * Cn * Sn;
    const float4* s0 = (const float4*)base;
    const float4* s1 = (const float4*)(base + Sn);
    const float4* s2 = (const float4*)(base + 2 * Sn);
    const float4* s3 = (const float4*)(base + 3 * Sn);
    const int qs = blockIdx.x * (PB / 4);
    unsigned int pk[PB / BT];   // 8 packed results per thread
    #pragma unroll
    for (int it = 0; it < PB / 4 / BT; ++it) {   // 2 iterations
        int q = qs + it * BT + t;
        float4 v0 = s0[q], v1 = s1[q], v2 = s2[q], v3 = s3[q];
        const float* a0 = &v0.x; const float* a1 = &v1.x;
        const float* a2 = &v2.x; const float* a3 = &v3.x;
        #pragma unroll
        for (int k = 0; k < 4; ++k) {
            int cm; float p;
            softmax_argmax4(a0[k], a1[k], a2[k], a3[k], &cm, &p);
            unsigned int pv = 0u;
            if (p > THRf) {
                unsigned int off = __float_as_uint(p) - 0x3F000000u;  // 1..0x800000
                atomicAdd(&lh[cm * NBINS + (int)(off >> 13)], 1u);    // no-return ds_add
                pv = (off << 2) | (unsigned int)cm;                   // 26 bits, nonzero
            }
            pk[it * 4 + k] = pv;
        }
    }
    __syncthreads();

    // phase 2: wave w (w<4) computes local cutoff for class w (64 lanes x 17 bins >= 1025).
    // Entries below the local cutoff have >=32 strictly-greater local entries ->
    // global rank >= 32 -> safe to drop. Union over blocks is a superset of top-32.
    {
        const int wave = t >> 6;
        if (wave < Cn) {
            const unsigned int* h = &lh[wave * NBINS];
            const int lo = lane * 17;
            unsigned int cs = 0;
            #pragma unroll
            for (int k = 0; k < 17; ++k) {
                int bin = lo + k;
                if (bin < NBINS) cs += h[bin];
            }
            unsigned int S = cs;  // inclusive suffix sum over lanes [lane..63]
            #pragma unroll
            for (int off = 1; off < 64; off <<= 1) {
                unsigned int v = __shfl_down(S, off, 64);
                if (lane + off < 64) S += v;
            }
            unsigned int suf = S - cs;
            if (S >= NPTS && suf < NPTS) {   // exactly one lane (when total >= 32)
                unsigned int acc = suf;
                int hi = min(lo + 16, NBINS - 1);
                for (int bin = hi; bin >= lo; --bin) {
                    acc += h[bin];
                    if (acc >= NPTS) {
                        lcut[wave] = (unsigned int)bin;
                        cls_cnt[wave] = acc;
                        break;
                    }
                }
            }
            if (lane == 0 && S < NPTS) cls_cnt[wave] = S;  // total<32: lcut=0, emit all
        }
    }
    __syncthreads();

    // phase 2.5: publish surviving bins (bin >= lcut, nonzero) into the global
    // per-(b,c) histogram == exactly the histogram of all emitted candidates.
    // Fire-and-forget device-scope atomics, ~35 per class per block.
    {
        const int wave = t >> 6;
        if (wave < Cn) {
            const unsigned int* h = &lh[wave * NBINS];
            unsigned int* g = gh + (size_t)(b * Cn + wave) * NBINS;
            for (int bin = (int)lcut[wave] + lane; bin < NBINS; bin += 64) {
                unsigned int v = h[bin];
                if (v) atomicAdd(&g[bin], v);
            }
        }
    }
    // reservation: one global atomic per (block, class) (device-scope sc1 RMW)
    if (t < Cn && cls_cnt[t] > 0)
        cls_base[t] = atomicAdd(&cnt[b * Cn + t], cls_cnt[t]);
    __syncthreads();

    // phase 3: emit survivors straight from registers (~130/block total).
    // Device-scope relaxed atomic stores (sc0 sc1): visible at the coherence point
    // once each wave's vmcnt drains -> no per-block release fence needed.
    #pragma unroll
    for (int j = 0; j < PB / BT; ++j) {
        unsigned int pv = pk[j];
        if (pv != 0u) {
            unsigned int cm = pv & 3u;
            if ((pv >> 15) >= lcut[cm]) {   // pv>>15 == p_off>>13 == bin
                unsigned int pos = cls_base[cm] + atomicAdd(&cls_pos[cm], 1u);
                if (pos < (unsigned int)cap) {
                    int it = j >> 2, k = j & 3;
                    unsigned int idx = (unsigned int)((qs + it * BT + t) * 4 + k);
                    unsigned long long packed =
                        ((unsigned long long)idx << 32) | (0x3F000000u + (pv >> 2));
                    __hip_atomic_store(
                        (unsigned long long*)&cand[(size_t)(b * Cn + cm) * cap + pos],
                        packed, __ATOMIC_RELAXED, __HIP_MEMORY_SCOPE_AGENT);
                }
            }
        }
    }

    // ---- epilogue: last FOUR finishers of this batch each select ONE class ----
    // __syncthreads() drains every wave's vmcnt (sc1 stores + gh/cnt atomics reach
    // the coherence point) before t==0 issues the done RMW -> release w/o wbl2.
    __syncthreads();
    if (t == 0) s_old = atomicAdd(&done[b], 1u);
    __syncthreads();
    const unsigned int NX = gridDim.x;
    if (s_old + 4u < NX) return;              // keep the last 4 increments
    const int csel = (int)(NX - 1u - s_old);  // unique in 0..3
    // spin until every block of this batch has released its results; we wait on
    // <=3 stragglers, all schedulable (>=NX-4 slots already freed) -> no deadlock.
    if (t == 0) {
        while (__hip_atomic_load(&done[b], __ATOMIC_RELAXED, __HIP_MEMORY_SCOPE_AGENT) < NX)
            __builtin_amdgcn_s_sleep(2);
    }
    __syncthreads();
    __threadfence();   // acquire (buffer_inv): 8 blocks device-wide pay this

    const int bc = b * Cn + csel;
    // load this class's global histogram (complete) into lh[0..NBINS)
    for (int j = t; j < NBINS; j += BT) lh[j] = gh[(size_t)bc * NBINS + j];
    if (t == 0) { s_T = 0u; s_m = 0u; }
    __syncthreads();
    const int n = min((int)cnt[bc], cap);

    // exact global cutoff: wave 0 scans the 1025 bins
    if (t < 64) {
        const int lo = lane * 17;
        unsigned int cs = 0;
        #pragma unroll
        for (int k = 0; k < 17; ++k) {
            int bin = lo + k;
            if (bin < NBINS) cs += lh[bin];
        }
        unsigned int S = cs;
        #pragma unroll
        for (int off = 1; off < 64; off <<= 1) {
            unsigned int v = __shfl_down(S, off, 64);
            if (lane + off < 64) S += v;
        }
        unsigned int suf = S - cs;
        if (S >= NPTS && suf < NPTS) {
            unsigned int acc = suf;
            int hi = min(lo + 16, NBINS - 1);
            for (int bin = hi; bin >= lo; --bin) {
                acc += lh[bin];
                if (acc >= NPTS) { s_T = (unsigned int)bin; break; }
            }
        }
        // S < NPTS: s_T stays 0 -> keep everything
    }
    __syncthreads();
    const unsigned int T = s_T;

    // single filtered pass, branch-free 8-deep load batches (true MLP; the R11
    // killer was guard-branches serializing the "unrolled" loads).
    {
        const uint2* src = cand + (size_t)bc * cap;
        for (int j0 = t; j0 < n; j0 += BT * 8) {
            uint2 e[8];
            #pragma unroll
            for (int k = 0; k < 8; ++k) {
                int j = j0 + k * BT;
                e[k] = src[j < n ? j : (n - 1)];   // clamped: load always issues
            }
            #pragma unroll
            for (int k = 0; k < 8; ++k) {
                int j = j0 + k * BT;
                if (j < n && (unsigned int)bin_of_bits(e[k].x) >= T) {
                    unsigned int pos = atomicAdd(&s_m, 1u);
                    if (pos < FB) fbuf[pos] = e[k];
                }
            }
        }
    }
    __syncthreads();

    // exact rank with jax tie-break (higher prob first; equal prob -> lower idx
    // first); ranks are distinct (idx unique per class). ~80 survivors, 1 pass.
    const int m = min((int)s_m, FB);
    const int vn = min(n, NPTS);
    if (t == 0)
        __hip_atomic_store(&validn[bc], (unsigned int)vn,
                           __ATOMIC_RELAXED, __HIP_MEMORY_SCOPE_AGENT);
    for (int i = t; i < m; i += BT) {
        uint2 e = fbuf[i];
        int rank = 0;
        for (int j = 0; j < m; ++j) {
            uint2 o = fbuf[j];
            rank += (int)((o.x > e.x) || (o.x == e.x && o.y < e.y));
        }
        if (rank < vn) {
            unsigned long long packed = ((unsigned long long)e.y << 32) | e.x;
            __hip_atomic_store((unsigned long long*)&topk[bc * NPTS + rank],
                               packed, __ATOMIC_RELAXED, __HIP_MEMORY_SCOPE_AGENT);
        }
    }

    // ---- final emit: last class-finisher of this batch writes the 128 slots ----
    __syncthreads();   // drain sc1 topk/validn stores before done2 RMW (release)
    if (t == 0) s_old = atomicAdd(&done2[b], 1u);
    __syncthreads();
    if (s_old != 3u) return;
    __threadfence();   // acquire: see the other 3 classes' topk/validn

    if (t == 0) {
        int acc = 0;
        for (int oc = 0; oc < Cn; ++oc) {
            pre[oc] = acc;
            acc += (int)validn[b * Cn + ((oc + 1) & 3)];   // class order [1,2,3,0]
        }
        pre[Cn] = acc;
    }
    __syncthreads();

    if (t < Cn * NPTS) {
        const int j = t;
        int label = -1, z = 0, y = 0, x = 0;
        if (j < pre[Cn]) {
            int oc = 0;
            while (j >= pre[oc + 1]) ++oc;
            int c = (oc + 1) & 3;
            int r = j - pre[oc];
            uint2 e = topk[(b * Cn + c) * NPTS + r];
            int idx = (int)e.y;
            z = idx >> 14;          // idx / (128*128)
            y = (idx >> 7) & 127;   // (idx / 128) % 128
            x = idx & 127;          // idx % 128
            label = c;
        }
        int* coords = out;                       // 2*128*3 = 768 ints
        int* labels = out + Bn * Cn * NPTS * 3;  // then 2*128 = 256 ints
        int bo = b * Cn * NPTS + j;
        coords[bo * 3 + 0] = z;
        coords[bo * 3 + 1] = y;
        coords[bo * 3 + 2] = x;
        labels[bo] = label;
    }
}

extern "C" void kernel_launch(void* const* d_in, const int* in_sizes, int n_in,
                              void* d_out, int out_size, void* d_ws, size_t ws_size,
                              hipStream_t stream) {
    const float* logits = (const float*)d_in[0];
    int* out = (int*)d_out;

    // Workspace layout (zeroed region first, contiguous)
    unsigned int* cnt = (unsigned int*)d_ws;             // 8 u32   @0
    unsigned int* done = cnt + Bn * Cn;                  // 2 u32   @32
    unsigned int* done2 = done + Bn;                     // 2 u32   @40
    unsigned int* gh = done2 + Bn;                       // 8*1025  @48
    unsigned int* validn = gh + Bn * Cn * NBINS;         // 8 u32   @32848
    uint2* topk = (uint2*)(validn + Bn * Cn);            // 256 uint2 @32880 (8-aligned)
    uint2* cand = topk + Bn * Cn * NPTS;                 // @34928
    size_t fixed = (size_t)((char*)cand - (char*)d_ws);
    int cap = (int)((ws_size - fixed) / (Bn * Cn * sizeof(uint2)));
    if (cap > (1 << 18)) cap = 1 << 18;   // 256k entries/bc >> the ~18k expected
    if (cap < 4096) cap = 4096;

    // Zero cnt+done+done2+gh (contiguous, ~33 KB); validn/topk are fully
    // overwritten each run (workspace is harness-poisoned every iter).
    hipMemsetAsync(cnt, 0,
                   (size_t)(Bn * Cn + Bn + Bn + Bn * Cn * NBINS) * sizeof(unsigned int),
                   stream);

    dim3 grid(Sn / PB, Bn);   // (512, 2) = 1024 blocks
    fused_kernel<<<grid, BT, 0, stream>>>(logits, cnt, gh, cand, cap,
                                          done, done2, validn, topk, out);
}